// Round 20
// baseline (189.155 us; speedup 1.0000x reference)
//
#include <hip/hip_runtime.h>
#include <stdint.h>

typedef float  f32x4  __attribute__((ext_vector_type(4)));
typedef short  s16x4  __attribute__((ext_vector_type(4)));
typedef short  s16x8  __attribute__((ext_vector_type(8)));

#define S_LEN 2048
#define D_K   64
#define NBH   32
#define VT_STRIDE (S_LEN + 32)
#define MFMA  __builtin_amdgcn_mfma_f32_16x16x32_bf16

__device__ __forceinline__ short f2bf(float f) {
    uint32_t u = __builtin_bit_cast(uint32_t, f);
    u += 0x7fffu + ((u >> 16) & 1u);           // RNE
    return (short)(u >> 16);
}
__device__ __forceinline__ s16x4 cvt4(float4 f) {
    s16x4 r; r[0] = f2bf(f.x); r[1] = f2bf(f.y); r[2] = f2bf(f.z); r[3] = f2bf(f.w);
    return r;
}
__device__ __forceinline__ s16x8 cat(s16x4 a, s16x4 b) {
    return __builtin_shufflevector(a, b, 0, 1, 2, 3, 4, 5, 6, 7);
}
__device__ __forceinline__ void nt_store4(float* p, f32x4 v) {
    __builtin_nontemporal_store(v, (f32x4*)p);
}

// ---- pre-pass: K -> bf16 FRAG-PERMUTED rows, V -> bf16 transposed, k-permuted ----
__global__ __launch_bounds__(256) void preconv(
    const float* __restrict__ K, const float* __restrict__ V,
    short* __restrict__ Kb, short* __restrict__ VT)
{
    const int bh  = blockIdx.x >> 6;
    const int seg = blockIdx.x & 63;
    const int tid = threadIdx.x;
    const float* Ks = K + ((size_t)bh * S_LEN + seg * 32) * D_K;
    const float* Vs = V + ((size_t)bh * S_LEN + seg * 32) * D_K;
    short* Kd  = Kb + ((size_t)bh * S_LEN + seg * 32) * D_K;
    short* VTd = VT + (size_t)bh * D_K * VT_STRIDE + seg * 32;

    for (int i = tid; i < 512; i += 256) {
        const int r = i >> 4, ci = i & 15;
        float4 f = *(const float4*)(Ks + r * D_K + (ci << 2));
        const int j = ((ci & 3) << 1) + ((ci >> 2) & 1) + ((ci >> 3) << 3);
        *(s16x4*)(Kd + r * D_K + (j << 2)) = cvt4(f);
    }
    for (int i = tid; i < 512; i += 256) {
        const int r = i & 31, c = (i >> 5) << 2;
        float4 f = *(const float4*)(Vs + r * D_K + c);
        const int rp = (((r & 15) >> 2) << 3) + (((r >> 4) & 1) << 2) + (r & 3);
        VTd[(size_t)(c + 0) * VT_STRIDE + rp] = f2bf(f.x);
        VTd[(size_t)(c + 1) * VT_STRIDE + rp] = f2bf(f.y);
        VTd[(size_t)(c + 2) * VT_STRIDE + rp] = f2bf(f.z);
        VTd[(size_t)(c + 3) * VT_STRIDE + rp] = f2bf(f.w);
    }
}

// ---- paired-strip kernel, 8 waves: k-range split 8 ways (half the chain of R19) ----
#define PSTR 521     // odd stride -> conflict-free staging banks
#define CHUNK 16     // tiles per flush chunk (512 cols)
__global__ __launch_bounds__(512) void attn_pair8(
    const float* __restrict__ Q, const short* __restrict__ Kb,
    const short* __restrict__ VT, float* __restrict__ outC,
    float* __restrict__ outS)
{
    __shared__ float pstg[32 * PSTR];        // 66.7 KB; reused as [4][32][65] for combine
    __shared__ float lbuf[8][32];

    const int tid = threadIdx.x, lane = tid & 63, wv = tid >> 6;   // 0..7
    const int xcd = blockIdx.x & 7;
    const int idx = blockIdx.x >> 3;             // 0..255
    const int bh  = (xcd << 2) + (idx >> 6);     // 0..31
    const int j   = 63 - (idx & 63);             // heavy pairs first
    const int q0  = j << 5;                      // strip a rows q0..+15, b rows +16..+31
    const int l15 = lane & 15;
    const int g   = lane >> 4;
    const int d0  = g << 2;
    const int qa  = q0 + l15;

    const short* Kbh = Kb + (size_t)bh * S_LEN * D_K;
    const short* VTh = VT + (size_t)bh * D_K * VT_STRIDE;
    float* outSb = outS + (size_t)bh * S_LEN * S_LEN;
    float* outCb = outC + (size_t)bh * S_LEN * D_K;

    s16x8 qf0a, qf1a, qf0b, qf1b;
    {
        const float4* qp = (const float4*)(Q + ((size_t)bh * S_LEN + qa) * D_K);
        qf0a = cat(cvt4(qp[g]),     cvt4(qp[g + 4]));
        qf1a = cat(cvt4(qp[g + 8]), cvt4(qp[g + 12]));
        const float4* qp2 = (const float4*)(Q + ((size_t)bh * S_LEN + qa + 16) * D_K);
        qf0b = cat(cvt4(qp2[g]),     cvt4(qp2[g + 4]));
        qf1b = cat(cvt4(qp2[g + 8]), cvt4(qp2[g + 12]));
    }

    const int ntiles = j + 1;
    const float scale = 0.125f;

    // ================= phase 1: row sums both strips (3-deep, stride 8) =================
    float la = 0.f, lb = 0.f;
    {
        auto LD = [&](s16x8& r0, s16x8& r1, s16x8& r2, s16x8& r3, int t) {
            const short* p = Kbh + (((size_t)t << 5) + l15) * D_K + (g << 3);
            r0 = *(const s16x8*)(p);
            r1 = *(const s16x8*)(p + 32);
            r2 = *(const s16x8*)(p + 16 * D_K);
            r3 = *(const s16x8*)(p + 16 * D_K + 32);
        };
        auto SUM = [&](s16x8 r0, s16x8 r1, s16x8 r2, s16x8 r3, int T) {
            f32x4 a0 = {0.f,0.f,0.f,0.f}, a1 = a0, b0 = a0, b1 = a0;
            a0 = MFMA(r0, qf0a, a0, 0,0,0);
            a0 = MFMA(r1, qf1a, a0, 0,0,0);
            a1 = MFMA(r2, qf0a, a1, 0,0,0);
            a1 = MFMA(r3, qf1a, a1, 0,0,0);
            b0 = MFMA(r0, qf0b, b0, 0,0,0);
            b0 = MFMA(r1, qf1b, b0, 0,0,0);
            b1 = MFMA(r2, qf0b, b1, 0,0,0);
            b1 = MFMA(r3, qf1b, b1, 0,0,0);
            if (T < j) {
                #pragma unroll
                for (int r = 0; r < 4; ++r) {
                    la += __expf(a0[r] * scale) + __expf(a1[r] * scale);
                    lb += __expf(b0[r] * scale) + __expf(b1[r] * scale);
                }
            } else {
                const int kb0 = (T << 5) + d0;
                #pragma unroll
                for (int r = 0; r < 4; ++r) {
                    const bool c = (kb0 + r) <= qa;
                    if (c) la += __expf(a0[r] * scale);
                    lb += __expf(b0[r] * scale);
                    if (c) lb += __expf(b1[r] * scale);
                }
            }
        };
        s16x8 A0,A1,A2,A3, B0,B1,B2,B3, C0,C1,C2,C3;
        int t = wv;
        if (t < ntiles) {
            LD(A0,A1,A2,A3, t);
            if (t + 8 < ntiles)  LD(B0,B1,B2,B3, t + 8);
            if (t + 16 < ntiles) LD(C0,C1,C2,C3, t + 16);
            for (;;) {
                SUM(A0,A1,A2,A3, t);
                t += 8;
                if (t >= ntiles) break;
                if (t + 16 < ntiles) LD(A0,A1,A2,A3, t + 16);
                SUM(B0,B1,B2,B3, t);
                t += 8;
                if (t >= ntiles) break;
                if (t + 16 < ntiles) LD(B0,B1,B2,B3, t + 16);
                SUM(C0,C1,C2,C3, t);
                t += 8;
                if (t >= ntiles) break;
                if (t + 16 < ntiles) LD(C0,C1,C2,C3, t + 16);
            }
        }
    }
    la += __shfl_xor(la, 16); la += __shfl_xor(la, 32);
    lb += __shfl_xor(lb, 16); lb += __shfl_xor(lb, 32);
    if (lane < 16) { lbuf[wv][l15] = la; lbuf[wv][16 + l15] = lb; }
    __syncthreads();
    float sa = 0.f, sb2 = 0.f;
    #pragma unroll
    for (int w = 0; w < 8; ++w) { sa += lbuf[w][l15]; sb2 += lbuf[w][16 + l15]; }
    const float rinva = 1.f / sa;
    const float rinvb = 1.f / sb2;

    // ===== phase 2: shared K/V -> P both strips + PV; chunked nt flush =====
    f32x4 cxa0 = {0.f,0.f,0.f,0.f}, cxa1 = cxa0, cxa2 = cxa0, cxa3 = cxa0;
    f32x4 cxb0 = cxa0, cxb1 = cxa0, cxb2 = cxa0, cxb3 = cxa0;
    {
        s16x8 k0[4], v0[4], k1[4], v1[4];

        auto LDK = [&](s16x8* kk, s16x8* vv, int t) {
            const short* kp = Kbh + (((size_t)t << 5) + l15) * D_K + (g << 3);
            kk[0] = *(const s16x8*)(kp);
            kk[1] = *(const s16x8*)(kp + 32);
            kk[2] = *(const s16x8*)(kp + 16 * D_K);
            kk[3] = *(const s16x8*)(kp + 16 * D_K + 32);
            const short* vp = VTh + (size_t)l15 * VT_STRIDE + (t << 5) + (g << 3);
            vv[0] = *(const s16x8*)(vp);
            vv[1] = *(const s16x8*)(vp + 16 * VT_STRIDE);
            vv[2] = *(const s16x8*)(vp + 32 * VT_STRIDE);
            vv[3] = *(const s16x8*)(vp + 48 * VT_STRIDE);
        };
        auto CMPS = [&](const s16x8* kk, const s16x8* vv, int T, int tt) {
            f32x4 a0 = {0.f,0.f,0.f,0.f}, a1 = a0, b0 = a0, b1 = a0;
            a0 = MFMA(kk[0], qf0a, a0, 0,0,0);
            a0 = MFMA(kk[1], qf1a, a0, 0,0,0);
            a1 = MFMA(kk[2], qf0a, a1, 0,0,0);
            a1 = MFMA(kk[3], qf1a, a1, 0,0,0);
            b0 = MFMA(kk[0], qf0b, b0, 0,0,0);
            b0 = MFMA(kk[1], qf1b, b0, 0,0,0);
            b1 = MFMA(kk[2], qf0b, b1, 0,0,0);
            b1 = MFMA(kk[3], qf1b, b1, 0,0,0);
            f32x4 pa0, pa1, pb0, pb1;
            s16x8 pfa, pfb;
            if (T < j) {
                #pragma unroll
                for (int r = 0; r < 4; ++r) {
                    float ea0 = __expf(a0[r] * scale) * rinva;
                    float ea1 = __expf(a1[r] * scale) * rinva;
                    float eb0 = __expf(b0[r] * scale) * rinvb;
                    float eb1 = __expf(b1[r] * scale) * rinvb;
                    pa0[r] = ea0; pa1[r] = ea1; pb0[r] = eb0; pb1[r] = eb1;
                    pfa[r] = f2bf(ea0); pfa[4 + r] = f2bf(ea1);
                    pfb[r] = f2bf(eb0); pfb[4 + r] = f2bf(eb1);
                }
            } else {
                const int kb0 = (T << 5) + d0;
                #pragma unroll
                for (int r = 0; r < 4; ++r) {
                    const bool c = (kb0 + r) <= qa;
                    float ea0 = c ? __expf(a0[r] * scale) * rinva : 0.f;
                    float eb0 = __expf(b0[r] * scale) * rinvb;
                    float eb1 = c ? __expf(b1[r] * scale) * rinvb : 0.f;
                    pa0[r] = ea0; pa1[r] = 0.f; pb0[r] = eb0; pb1[r] = eb1;
                    pfa[r] = f2bf(ea0); pfa[4 + r] = 0;
                    pfb[r] = f2bf(eb0); pfb[4 + r] = f2bf(eb1);
                }
            }
            float* sA = &pstg[l15 * PSTR + (tt << 5) + d0];
            float* sB = &pstg[(16 + l15) * PSTR + (tt << 5) + d0];
            *(f32x4*)(sA)      = pa0;
            *(f32x4*)(sA + 16) = pa1;
            *(f32x4*)(sB)      = pb0;
            *(f32x4*)(sB + 16) = pb1;
            cxa0 = MFMA(pfa, vv[0], cxa0, 0,0,0);
            cxa1 = MFMA(pfa, vv[1], cxa1, 0,0,0);
            cxa2 = MFMA(pfa, vv[2], cxa2, 0,0,0);
            cxa3 = MFMA(pfa, vv[3], cxa3, 0,0,0);
            cxb0 = MFMA(pfb, vv[0], cxb0, 0,0,0);
            cxb1 = MFMA(pfb, vv[1], cxb1, 0,0,0);
            cxb2 = MFMA(pfb, vv[2], cxb2, 0,0,0);
            cxb3 = MFMA(pfb, vv[3], cxb3, 0,0,0);
        };

        if (wv < ntiles)     LDK(k0, v0, wv);
        if (wv + 8 < ntiles) LDK(k1, v1, wv + 8);

        for (int cb = 0; cb < ntiles; cb += CHUNK) {
            const int tA = cb + wv, tB = cb + 8 + wv;
            if (tA < ntiles) CMPS(k0, v0, tA, tA - cb);
            const int nA = cb + 16 + wv;
            if (nA < ntiles) LDK(k0, v0, nA);
            if (tB < ntiles) CMPS(k1, v1, tB, tB - cb);
            const int nB = cb + 24 + wv;
            if (nB < ntiles) LDK(k1, v1, nB);
            asm volatile("s_waitcnt lgkmcnt(0)" ::: "memory");
            __builtin_amdgcn_s_barrier();
            // flush: 8 waves x 4 rows each; per row up to 2x1KB sequential stores
            const int rem = ntiles - cb;
            const int W = ((rem < CHUNK) ? rem : CHUNK) << 5;
            const size_t gb = (size_t)q0 * S_LEN + ((size_t)cb << 5);
            #pragma unroll
            for (int rr = 0; rr < 4; ++rr) {
                const int row = (rr << 3) + wv;                  // 0..31
                for (int c = lane << 2; c < W; c += 256)
                    nt_store4(outSb + gb + (size_t)row * S_LEN + c,
                              *(const f32x4*)&pstg[row * PSTR + c]);
            }
            asm volatile("s_waitcnt lgkmcnt(0)" ::: "memory");
            __builtin_amdgcn_s_barrier();
        }
    }

    // zero-fill masked region for all 32 rows (512 thr x 16B = 8KB per step)
    const int kz = ntiles << 5;
    const f32x4 z = {0.f,0.f,0.f,0.f};
    {
        const int c0 = tid << 2;
        for (int r = 0; r < 32; ++r) {
            float* rowp = outSb + (size_t)(q0 + r) * S_LEN;
            for (int k = kz + c0; k < S_LEN; k += 2048)
                nt_store4(rowp + k, z);
        }
    }

    // combine partial ctx across 8 waves: 3-stage via pstg as [4][32][65]
    __syncthreads();
    {
        float* cb2 = pstg;
        if (wv < 4) {
            const int base = wv * 2080;
            #pragma unroll
            for (int r = 0; r < 4; ++r) {
                cb2[base + (d0 + r) * 65 +  0 + l15] = cxa0[r];
                cb2[base + (d0 + r) * 65 + 16 + l15] = cxa1[r];
                cb2[base + (d0 + r) * 65 + 32 + l15] = cxa2[r];
                cb2[base + (d0 + r) * 65 + 48 + l15] = cxa3[r];
                cb2[base + (16 + d0 + r) * 65 +  0 + l15] = cxb0[r];
                cb2[base + (16 + d0 + r) * 65 + 16 + l15] = cxb1[r];
                cb2[base + (16 + d0 + r) * 65 + 32 + l15] = cxb2[r];
                cb2[base + (16 + d0 + r) * 65 + 48 + l15] = cxb3[r];
            }
        }
        __syncthreads();
        if (wv >= 4) {
            const int base = (wv - 4) * 2080;
            #pragma unroll
            for (int r = 0; r < 4; ++r) {
                cb2[base + (d0 + r) * 65 +  0 + l15] += cxa0[r];
                cb2[base + (d0 + r) * 65 + 16 + l15] += cxa1[r];
                cb2[base + (d0 + r) * 65 + 32 + l15] += cxa2[r];
                cb2[base + (d0 + r) * 65 + 48 + l15] += cxa3[r];
                cb2[base + (16 + d0 + r) * 65 +  0 + l15] += cxb0[r];
                cb2[base + (16 + d0 + r) * 65 + 16 + l15] += cxb1[r];
                cb2[base + (16 + d0 + r) * 65 + 32 + l15] += cxb2[r];
                cb2[base + (16 + d0 + r) * 65 + 48 + l15] += cxb3[r];
            }
        }
        __syncthreads();
        const int row = tid >> 4, dbase = (tid & 15) << 2;   // 32 rows x 16 thr
        f32x4 acc = *(const f32x4*)&cb2[0 * 2080 + row * 65 + dbase];
        #pragma unroll
        for (int w = 1; w < 4; ++w) {
            f32x4 p = *(const f32x4*)&cb2[w * 2080 + row * 65 + dbase];
            acc[0] += p[0]; acc[1] += p[1]; acc[2] += p[2]; acc[3] += p[3];
        }
        *(f32x4*)(outCb + (size_t)(q0 + row) * D_K + dbase) = acc;
    }
}

// ---------------- fallback (R0 kernel, proven) if ws too small ----------------
#define KSTRIDE 68
#define VSTRIDE 36
__global__ __launch_bounds__(256) void attn_causal_fb(
    const float* __restrict__ Q, const float* __restrict__ K,
    const float* __restrict__ V, float* __restrict__ outC,
    float* __restrict__ outS)
{
    __shared__ short Klds[32 * KSTRIDE];
    __shared__ short Vlds[64 * VSTRIDE];
    const int bh = blockIdx.x >> 5, q0 = (blockIdx.x & 31) << 6;
    const int tid = threadIdx.x, lane = tid & 63, wv = tid >> 6;
    const int q0w = q0 + (wv << 4), l15 = lane & 15, d0 = (lane >> 4) << 2;
    const int qg = q0w + l15, qhi = q0w + 15;
    const float* Kb = K + (size_t)bh * S_LEN * D_K;
    const float* Vb = V + (size_t)bh * S_LEN * D_K;
    float* outSb = outS + (size_t)bh * S_LEN * S_LEN;
    float* outCb = outC + (size_t)bh * S_LEN * D_K;
    s16x8 qf0, qf1;
    {
        const float4* qp = (const float4*)(Q + ((size_t)bh * S_LEN + qg) * D_K);
        qf0 = cat(cvt4(qp[d0 >> 2]), cvt4(qp[(d0 + 16) >> 2]));
        qf1 = cat(cvt4(qp[(d0 + 32) >> 2]), cvt4(qp[(d0 + 48) >> 2]));
    }
    const int npairs = (q0 >> 5) + 2;
    const float scale = 0.125f;
    float lsum = 0.f;
    for (int p = 0; p < npairs; ++p) {
        const int k0 = p << 5;
        for (int i = tid; i < 512; i += 256) {
            const int r = i >> 4, c = (i & 15) << 2;
            float4 f = *(const float4*)(Kb + (size_t)(k0 + r) * D_K + c);
            *(s16x4*)&Klds[r * KSTRIDE + c] = cvt4(f);
        }
        __syncthreads();
        if (k0 <= qhi) {
            #pragma unroll
            for (int s = 0; s < 2; ++s) {
                const short* kp = &Klds[(16 * s + l15) * KSTRIDE + d0];
                s16x8 a0 = cat(*(const s16x4*)kp, *(const s16x4*)(kp + 16));
                s16x8 a1 = cat(*(const s16x4*)(kp + 32), *(const s16x4*)(kp + 48));
                f32x4 c1 = {0.f,0.f,0.f,0.f};
                c1 = MFMA(a0, qf0, c1, 0,0,0);
                c1 = MFMA(a1, qf1, c1, 0,0,0);
                const int kbase = k0 + 16 * s + d0;
                #pragma unroll
                for (int r = 0; r < 4; ++r)
                    if (kbase + r <= qg) lsum += __expf(c1[r] * scale);
            }
        }
        __syncthreads();
    }
    lsum += __shfl_xor(lsum, 16);
    lsum += __shfl_xor(lsum, 32);
    const float rinv = 1.f / lsum;
    f32x4 ctx[4] = {{0,0,0,0},{0,0,0,0},{0,0,0,0},{0,0,0,0}};
    for (int p = 0; p < npairs; ++p) {
        const int k0 = p << 5;
        for (int i = tid; i < 512; i += 256) {
            const int r = i >> 4, c = (i & 15) << 2;
            float4 f = *(const float4*)(Kb + (size_t)(k0 + r) * D_K + c);
            *(s16x4*)&Klds[r * KSTRIDE + c] = cvt4(f);
            float4 gg = *(const float4*)(Vb + (size_t)(k0 + r) * D_K + c);
            Vlds[(c + 0) * VSTRIDE + r] = f2bf(gg.x);
            Vlds[(c + 1) * VSTRIDE + r] = f2bf(gg.y);
            Vlds[(c + 2) * VSTRIDE + r] = f2bf(gg.z);
            Vlds[(c + 3) * VSTRIDE + r] = f2bf(gg.w);
        }
        __syncthreads();
        if (k0 <= qhi) {
            s16x8 pf;
            #pragma unroll
            for (int s = 0; s < 2; ++s) {
                const short* kp = &Klds[(16 * s + l15) * KSTRIDE + d0];
                s16x8 a0 = cat(*(const s16x4*)kp, *(const s16x4*)(kp + 16));
                s16x8 a1 = cat(*(const s16x4*)(kp + 32), *(const s16x4*)(kp + 48));
                f32x4 c1 = {0.f,0.f,0.f,0.f};
                c1 = MFMA(a0, qf0, c1, 0,0,0);
                c1 = MFMA(a1, qf1, c1, 0,0,0);
                const int kbase = k0 + 16 * s + d0;
                f32x4 pw;
                #pragma unroll
                for (int r = 0; r < 4; ++r) {
                    float pe = (kbase + r <= qg) ? __expf(c1[r] * scale) * rinv : 0.f;
                    pw[r] = pe;
                    pf[4 * s + r] = f2bf(pe);
                }
                *(f32x4*)(outSb + (size_t)qg * S_LEN + kbase) = pw;
            }
            #pragma unroll
            for (int db = 0; db < 4; ++db) {
                const short* vp = &Vlds[(db * 16 + l15) * VSTRIDE + d0];
                s16x8 b = cat(*(const s16x4*)vp, *(const s16x4*)(vp + 16));
                ctx[db] = MFMA(pf, b, ctx[db], 0,0,0);
            }
        }
        __syncthreads();
    }
    #pragma unroll
    for (int db = 0; db < 4; ++db)
        #pragma unroll
        for (int r = 0; r < 4; ++r)
            outCb[(size_t)(q0w + d0 + r) * D_K + db * 16 + l15] = ctx[db][r];
    const int kz = ((qhi >> 5) + 1) << 5;
    const f32x4 z = {0.f,0.f,0.f,0.f};
    for (int r = 0; r < 16; ++r) {
        float* rowp = outSb + (size_t)(q0w + r) * S_LEN;
        for (int k = kz + (lane << 2); k < S_LEN; k += 256)
            *(f32x4*)(rowp + k) = z;
    }
}

extern "C" void kernel_launch(void* const* d_in, const int* in_sizes, int n_in,
                              void* d_out, int out_size, void* d_ws, size_t ws_size,
                              hipStream_t stream) {
    const float* Q = (const float*)d_in[0];
    const float* K = (const float*)d_in[1];
    const float* V = (const float*)d_in[2];
    float* outC = (float*)d_out;
    float* outS = (float*)d_out + (size_t)NBH * S_LEN * D_K;

    const size_t kb_elems = (size_t)NBH * S_LEN * D_K;
    const size_t vt_elems = (size_t)NBH * D_K * VT_STRIDE;
    const size_t need = (kb_elems + vt_elems) * sizeof(short);

    if (ws_size >= need) {
        short* Kb = (short*)d_ws;
        short* VT = Kb + kb_elems;
        preconv<<<dim3(NBH * 64), dim3(256), 0, stream>>>(K, V, Kb, VT);
        attn_pair8<<<dim3(2048), dim3(512), 0, stream>>>(Q, Kb, VT, outC, outS);
    } else {
        attn_causal_fb<<<dim3(1024), dim3(256), 0, stream>>>(Q, K, V, outC, outS);
    }
}

// Round 22
// 163.118 us; speedup vs baseline: 1.1596x; 1.1596x over previous
//
#include <hip/hip_runtime.h>
#include <stdint.h>

typedef float  f32x4  __attribute__((ext_vector_type(4)));
typedef short  s16x4  __attribute__((ext_vector_type(4)));
typedef short  s16x8  __attribute__((ext_vector_type(8)));

#define S_LEN 2048
#define D_K   64
#define NBH   32
#define VT_STRIDE (S_LEN + 32)
#define MFMA  __builtin_amdgcn_mfma_f32_16x16x32_bf16

__device__ __forceinline__ short f2bf(float f) {
    uint32_t u = __builtin_bit_cast(uint32_t, f);
    u += 0x7fffu + ((u >> 16) & 1u);           // RNE
    return (short)(u >> 16);
}
__device__ __forceinline__ s16x4 cvt4(float4 f) {
    s16x4 r; r[0] = f2bf(f.x); r[1] = f2bf(f.y); r[2] = f2bf(f.z); r[3] = f2bf(f.w);
    return r;
}
__device__ __forceinline__ s16x8 cat(s16x4 a, s16x4 b) {
    return __builtin_shufflevector(a, b, 0, 1, 2, 3, 4, 5, 6, 7);
}
__device__ __forceinline__ void nt_store4(float* p, f32x4 v) {
    __builtin_nontemporal_store(v, (f32x4*)p);
}

// ---- pre-pass: K -> bf16 FRAG-PERMUTED rows, V -> bf16 transposed, k-permuted ----
__global__ __launch_bounds__(256) void preconv(
    const float* __restrict__ K, const float* __restrict__ V,
    short* __restrict__ Kb, short* __restrict__ VT)
{
    const int bh  = blockIdx.x >> 6;
    const int seg = blockIdx.x & 63;
    const int tid = threadIdx.x;
    const float* Ks = K + ((size_t)bh * S_LEN + seg * 32) * D_K;
    const float* Vs = V + ((size_t)bh * S_LEN + seg * 32) * D_K;
    short* Kd  = Kb + ((size_t)bh * S_LEN + seg * 32) * D_K;
    short* VTd = VT + (size_t)bh * D_K * VT_STRIDE + seg * 32;

    for (int i = tid; i < 512; i += 256) {
        const int r = i >> 4, ci = i & 15;
        float4 f = *(const float4*)(Ks + r * D_K + (ci << 2));
        const int jj = ((ci & 3) << 1) + ((ci >> 2) & 1) + ((ci >> 3) << 3);
        *(s16x4*)(Kd + r * D_K + (jj << 2)) = cvt4(f);
    }
    for (int i = tid; i < 512; i += 256) {
        const int r = i & 31, c = (i >> 5) << 2;
        float4 f = *(const float4*)(Vs + r * D_K + c);
        const int rp = (((r & 15) >> 2) << 3) + (((r >> 4) & 1) << 2) + (r & 3);
        VTd[(size_t)(c + 0) * VT_STRIDE + rp] = f2bf(f.x);
        VTd[(size_t)(c + 1) * VT_STRIDE + rp] = f2bf(f.y);
        VTd[(size_t)(c + 2) * VT_STRIDE + rp] = f2bf(f.z);
        VTd[(size_t)(c + 3) * VT_STRIDE + rp] = f2bf(f.w);
    }
}

// ---- quad-strip kernel: strips 4qj..4qj+3 (64 rows) share every K/V tile load ----
#define PSTR 261     // odd stride -> conflict-free staging banks
#define CHUNK 8      // tiles per flush chunk (256 cols)
__global__ __launch_bounds__(256) void attn_quad(
    const float* __restrict__ Q, const short* __restrict__ Kb,
    const short* __restrict__ VT, float* __restrict__ outC,
    float* __restrict__ outS)
{
    __shared__ float pstg[64 * PSTR];        // 66.8 KB; reused as [4][64][65] for combine
    __shared__ float lbuf[4][64];

    const int tid = threadIdx.x, lane = tid & 63, wv = tid >> 6;
    const int xcd = blockIdx.x & 7;
    const int idx = blockIdx.x >> 3;             // 0..127
    const int bh  = (xcd << 2) + (idx >> 5);     // 0..31
    const int qj  = 31 - (idx & 31);             // heavy quads first
    const int q0  = qj << 6;                     // strips a,b,c,d = rows q0+0/16/32/48
    const int l15 = lane & 15;
    const int g   = lane >> 4;
    const int d0  = g << 2;
    const int qa  = q0 + l15;

    const short* Kbh = Kb + (size_t)bh * S_LEN * D_K;
    const short* VTh = VT + (size_t)bh * D_K * VT_STRIDE;
    float* outSb = outS + (size_t)bh * S_LEN * S_LEN;
    float* outCb = outC + (size_t)bh * S_LEN * D_K;

    s16x8 qfa0, qfa1, qfb0, qfb1, qfc0, qfc1, qfd0, qfd1;
    {
        const float4* qp = (const float4*)(Q + ((size_t)bh * S_LEN + qa) * D_K);
        qfa0 = cat(cvt4(qp[g]),     cvt4(qp[g + 4]));
        qfa1 = cat(cvt4(qp[g + 8]), cvt4(qp[g + 12]));
        qp = (const float4*)(Q + ((size_t)bh * S_LEN + qa + 16) * D_K);
        qfb0 = cat(cvt4(qp[g]),     cvt4(qp[g + 4]));
        qfb1 = cat(cvt4(qp[g + 8]), cvt4(qp[g + 12]));
        qp = (const float4*)(Q + ((size_t)bh * S_LEN + qa + 32) * D_K);
        qfc0 = cat(cvt4(qp[g]),     cvt4(qp[g + 4]));
        qfc1 = cat(cvt4(qp[g + 8]), cvt4(qp[g + 12]));
        qp = (const float4*)(Q + ((size_t)bh * S_LEN + qa + 48) * D_K);
        qfd0 = cat(cvt4(qp[g]),     cvt4(qp[g + 4]));
        qfd1 = cat(cvt4(qp[g + 8]), cvt4(qp[g + 12]));
    }

    const int jj = qj << 1;                      // diagonal-A tile index
    const int ntiles = jj + 2;                   // tiles 0..jj-1 full, jj diagA, jj+1 diagB
    const float scale = 0.125f;

    // ================= phase 1: row sums for 4 strips (3-deep pipeline) =================
    float la = 0.f, lb = 0.f, lc = 0.f, ld = 0.f;
    {
        auto LD = [&](s16x8& r0, s16x8& r1, s16x8& r2, s16x8& r3, int t) {
            const short* p = Kbh + (((size_t)t << 5) + l15) * D_K + (g << 3);
            r0 = *(const s16x8*)(p);
            r1 = *(const s16x8*)(p + 32);
            r2 = *(const s16x8*)(p + 16 * D_K);
            r3 = *(const s16x8*)(p + 16 * D_K + 32);
        };
        auto SUM = [&](s16x8 r0, s16x8 r1, s16x8 r2, s16x8 r3, int T) {
            f32x4 z4 = {0.f,0.f,0.f,0.f};
            f32x4 sc0 = z4, sc1 = z4, sd0 = z4, sd1 = z4;
            sc0 = MFMA(r0, qfc0, sc0, 0,0,0);
            sc0 = MFMA(r1, qfc1, sc0, 0,0,0);
            sc1 = MFMA(r2, qfc0, sc1, 0,0,0);
            sc1 = MFMA(r3, qfc1, sc1, 0,0,0);
            sd0 = MFMA(r0, qfd0, sd0, 0,0,0);
            sd0 = MFMA(r1, qfd1, sd0, 0,0,0);
            sd1 = MFMA(r2, qfd0, sd1, 0,0,0);
            sd1 = MFMA(r3, qfd1, sd1, 0,0,0);
            if (T <= jj) {
                f32x4 sa0 = z4, sa1 = z4, sb0 = z4, sb1 = z4;
                sa0 = MFMA(r0, qfa0, sa0, 0,0,0);
                sa0 = MFMA(r1, qfa1, sa0, 0,0,0);
                sa1 = MFMA(r2, qfa0, sa1, 0,0,0);
                sa1 = MFMA(r3, qfa1, sa1, 0,0,0);
                sb0 = MFMA(r0, qfb0, sb0, 0,0,0);
                sb0 = MFMA(r1, qfb1, sb0, 0,0,0);
                sb1 = MFMA(r2, qfb0, sb1, 0,0,0);
                sb1 = MFMA(r3, qfb1, sb1, 0,0,0);
                if (T < jj) {
                    #pragma unroll
                    for (int r = 0; r < 4; ++r) {
                        la += __expf(sa0[r] * scale) + __expf(sa1[r] * scale);
                        lb += __expf(sb0[r] * scale) + __expf(sb1[r] * scale);
                        lc += __expf(sc0[r] * scale) + __expf(sc1[r] * scale);
                        ld += __expf(sd0[r] * scale) + __expf(sd1[r] * scale);
                    }
                } else {   // diagA: a0 cond, a1 none; b0 full, b1 cond; c,d full
                    #pragma unroll
                    for (int r = 0; r < 4; ++r) {
                        const bool c = (d0 + r) <= l15;
                        if (c) la += __expf(sa0[r] * scale);
                        lb += __expf(sb0[r] * scale);
                        if (c) lb += __expf(sb1[r] * scale);
                        lc += __expf(sc0[r] * scale) + __expf(sc1[r] * scale);
                        ld += __expf(sd0[r] * scale) + __expf(sd1[r] * scale);
                    }
                }
            } else {       // diagB: a,b none; c0 cond, c1 none; d0 full, d1 cond
                #pragma unroll
                for (int r = 0; r < 4; ++r) {
                    const bool c = (d0 + r) <= l15;   // FIXED condition
                    if (c) lc += __expf(sc0[r] * scale);
                    ld += __expf(sd0[r] * scale);
                    if (c) ld += __expf(sd1[r] * scale);
                }
            }
        };
        s16x8 A0,A1,A2,A3, B0,B1,B2,B3, C0,C1,C2,C3;
        int t = wv;
        if (t < ntiles) {
            LD(A0,A1,A2,A3, t);
            if (t + 4 < ntiles) LD(B0,B1,B2,B3, t + 4);
            if (t + 8 < ntiles) LD(C0,C1,C2,C3, t + 8);
            for (;;) {
                SUM(A0,A1,A2,A3, t);
                t += 4;
                if (t >= ntiles) break;
                if (t + 8 < ntiles) LD(A0,A1,A2,A3, t + 8);
                SUM(B0,B1,B2,B3, t);
                t += 4;
                if (t >= ntiles) break;
                if (t + 8 < ntiles) LD(B0,B1,B2,B3, t + 8);
                SUM(C0,C1,C2,C3, t);
                t += 4;
                if (t >= ntiles) break;
                if (t + 8 < ntiles) LD(C0,C1,C2,C3, t + 8);
            }
        }
    }
    la += __shfl_xor(la, 16); la += __shfl_xor(la, 32);
    lb += __shfl_xor(lb, 16); lb += __shfl_xor(lb, 32);
    lc += __shfl_xor(lc, 16); lc += __shfl_xor(lc, 32);
    ld += __shfl_xor(ld, 16); ld += __shfl_xor(ld, 32);
    if (lane < 16) {
        lbuf[wv][l15] = la; lbuf[wv][16 + l15] = lb;
        lbuf[wv][32 + l15] = lc; lbuf[wv][48 + l15] = ld;
    }
    __syncthreads();
    const float rinva = 1.f / (lbuf[0][l15] + lbuf[1][l15] + lbuf[2][l15] + lbuf[3][l15]);
    const float rinvb = 1.f / (lbuf[0][16+l15] + lbuf[1][16+l15] + lbuf[2][16+l15] + lbuf[3][16+l15]);
    const float rinvc = 1.f / (lbuf[0][32+l15] + lbuf[1][32+l15] + lbuf[2][32+l15] + lbuf[3][32+l15]);
    const float rinvd = 1.f / (lbuf[0][48+l15] + lbuf[1][48+l15] + lbuf[2][48+l15] + lbuf[3][48+l15]);

    // ===== phase 2: shared K/V -> P for 4 strips + PV; chunked nt flush =====
    f32x4 z4 = {0.f,0.f,0.f,0.f};
    f32x4 cxa0 = z4, cxa1 = z4, cxa2 = z4, cxa3 = z4;
    f32x4 cxb0 = z4, cxb1 = z4, cxb2 = z4, cxb3 = z4;
    f32x4 cxc0 = z4, cxc1 = z4, cxc2 = z4, cxc3 = z4;
    f32x4 cxd0 = z4, cxd1 = z4, cxd2 = z4, cxd3 = z4;
    {
        s16x8 k0[4], v0[4], k1[4], v1[4];

        auto LDK = [&](s16x8* kk, s16x8* vv, int t) {
            const short* kp = Kbh + (((size_t)t << 5) + l15) * D_K + (g << 3);
            kk[0] = *(const s16x8*)(kp);
            kk[1] = *(const s16x8*)(kp + 32);
            kk[2] = *(const s16x8*)(kp + 16 * D_K);
            kk[3] = *(const s16x8*)(kp + 16 * D_K + 32);
            const short* vp = VTh + (size_t)l15 * VT_STRIDE + (t << 5) + (g << 3);
            vv[0] = *(const s16x8*)(vp);
            vv[1] = *(const s16x8*)(vp + 16 * VT_STRIDE);
            vv[2] = *(const s16x8*)(vp + 32 * VT_STRIDE);
            vv[3] = *(const s16x8*)(vp + 48 * VT_STRIDE);
        };
        auto CMPS = [&](const s16x8* kk, const s16x8* vv, int T, int tt) {
            f32x4 pa0, pa1, pb0, pb1, pc0, pc1, pd0, pd1;
            s16x8 pfa, pfb, pfc, pfd;
            f32x4 sc0 = z4, sc1 = z4, sd0 = z4, sd1 = z4;
            sc0 = MFMA(kk[0], qfc0, sc0, 0,0,0);
            sc0 = MFMA(kk[1], qfc1, sc0, 0,0,0);
            sc1 = MFMA(kk[2], qfc0, sc1, 0,0,0);
            sc1 = MFMA(kk[3], qfc1, sc1, 0,0,0);
            sd0 = MFMA(kk[0], qfd0, sd0, 0,0,0);
            sd0 = MFMA(kk[1], qfd1, sd0, 0,0,0);
            sd1 = MFMA(kk[2], qfd0, sd1, 0,0,0);
            sd1 = MFMA(kk[3], qfd1, sd1, 0,0,0);
            if (T <= jj) {
                f32x4 sa0 = z4, sa1 = z4, sb0 = z4, sb1 = z4;
                sa0 = MFMA(kk[0], qfa0, sa0, 0,0,0);
                sa0 = MFMA(kk[1], qfa1, sa0, 0,0,0);
                sa1 = MFMA(kk[2], qfa0, sa1, 0,0,0);
                sa1 = MFMA(kk[3], qfa1, sa1, 0,0,0);
                sb0 = MFMA(kk[0], qfb0, sb0, 0,0,0);
                sb0 = MFMA(kk[1], qfb1, sb0, 0,0,0);
                sb1 = MFMA(kk[2], qfb0, sb1, 0,0,0);
                sb1 = MFMA(kk[3], qfb1, sb1, 0,0,0);
                if (T < jj) {
                    #pragma unroll
                    for (int r = 0; r < 4; ++r) {
                        float e;
                        e = __expf(sa0[r]*scale)*rinva; pa0[r] = e; pfa[r]   = f2bf(e);
                        e = __expf(sa1[r]*scale)*rinva; pa1[r] = e; pfa[4+r] = f2bf(e);
                        e = __expf(sb0[r]*scale)*rinvb; pb0[r] = e; pfb[r]   = f2bf(e);
                        e = __expf(sb1[r]*scale)*rinvb; pb1[r] = e; pfb[4+r] = f2bf(e);
                        e = __expf(sc0[r]*scale)*rinvc; pc0[r] = e; pfc[r]   = f2bf(e);
                        e = __expf(sc1[r]*scale)*rinvc; pc1[r] = e; pfc[4+r] = f2bf(e);
                        e = __expf(sd0[r]*scale)*rinvd; pd0[r] = e; pfd[r]   = f2bf(e);
                        e = __expf(sd1[r]*scale)*rinvd; pd1[r] = e; pfd[4+r] = f2bf(e);
                    }
                } else {   // diagA
                    #pragma unroll
                    for (int r = 0; r < 4; ++r) {
                        const bool c = (d0 + r) <= l15;
                        float e;
                        e = c ? __expf(sa0[r]*scale)*rinva : 0.f; pa0[r] = e; pfa[r] = f2bf(e);
                        pa1[r] = 0.f; pfa[4+r] = 0;
                        e = __expf(sb0[r]*scale)*rinvb;           pb0[r] = e; pfb[r] = f2bf(e);
                        e = c ? __expf(sb1[r]*scale)*rinvb : 0.f; pb1[r] = e; pfb[4+r] = f2bf(e);
                        e = __expf(sc0[r]*scale)*rinvc; pc0[r] = e; pfc[r]   = f2bf(e);
                        e = __expf(sc1[r]*scale)*rinvc; pc1[r] = e; pfc[4+r] = f2bf(e);
                        e = __expf(sd0[r]*scale)*rinvd; pd0[r] = e; pfd[r]   = f2bf(e);
                        e = __expf(sd1[r]*scale)*rinvd; pd1[r] = e; pfd[4+r] = f2bf(e);
                    }
                }
            } else {       // diagB: a,b zero; c0 cond, c1 none; d0 full, d1 cond
                #pragma unroll
                for (int r = 0; r < 4; ++r) {
                    const bool c = (d0 + r) <= l15;   // FIXED condition
                    pa0[r] = 0.f; pa1[r] = 0.f; pfa[r] = 0; pfa[4+r] = 0;
                    pb0[r] = 0.f; pb1[r] = 0.f; pfb[r] = 0; pfb[4+r] = 0;
                    float e;
                    e = c ? __expf(sc0[r]*scale)*rinvc : 0.f; pc0[r] = e; pfc[r] = f2bf(e);
                    pc1[r] = 0.f; pfc[4+r] = 0;
                    e = __expf(sd0[r]*scale)*rinvd;           pd0[r] = e; pfd[r] = f2bf(e);
                    e = c ? __expf(sd1[r]*scale)*rinvd : 0.f; pd1[r] = e; pfd[4+r] = f2bf(e);
                }
            }
            const int cbase = (tt << 5) + d0;
            float* s0 = &pstg[l15 * PSTR + cbase];
            *(f32x4*)(s0)      = pa0;
            *(f32x4*)(s0 + 16) = pa1;
            float* s1 = &pstg[(16 + l15) * PSTR + cbase];
            *(f32x4*)(s1)      = pb0;
            *(f32x4*)(s1 + 16) = pb1;
            float* s2 = &pstg[(32 + l15) * PSTR + cbase];
            *(f32x4*)(s2)      = pc0;
            *(f32x4*)(s2 + 16) = pc1;
            float* s3 = &pstg[(48 + l15) * PSTR + cbase];
            *(f32x4*)(s3)      = pd0;
            *(f32x4*)(s3 + 16) = pd1;
            cxa0 = MFMA(pfa, vv[0], cxa0, 0,0,0);
            cxa1 = MFMA(pfa, vv[1], cxa1, 0,0,0);
            cxa2 = MFMA(pfa, vv[2], cxa2, 0,0,0);
            cxa3 = MFMA(pfa, vv[3], cxa3, 0,0,0);
            cxb0 = MFMA(pfb, vv[0], cxb0, 0,0,0);
            cxb1 = MFMA(pfb, vv[1], cxb1, 0,0,0);
            cxb2 = MFMA(pfb, vv[2], cxb2, 0,0,0);
            cxb3 = MFMA(pfb, vv[3], cxb3, 0,0,0);
            cxc0 = MFMA(pfc, vv[0], cxc0, 0,0,0);
            cxc1 = MFMA(pfc, vv[1], cxc1, 0,0,0);
            cxc2 = MFMA(pfc, vv[2], cxc2, 0,0,0);
            cxc3 = MFMA(pfc, vv[3], cxc3, 0,0,0);
            cxd0 = MFMA(pfd, vv[0], cxd0, 0,0,0);
            cxd1 = MFMA(pfd, vv[1], cxd1, 0,0,0);
            cxd2 = MFMA(pfd, vv[2], cxd2, 0,0,0);
            cxd3 = MFMA(pfd, vv[3], cxd3, 0,0,0);
        };

        if (wv < ntiles)     LDK(k0, v0, wv);
        if (wv + 4 < ntiles) LDK(k1, v1, wv + 4);

        for (int cb = 0; cb < ntiles; cb += CHUNK) {
            const int tA = cb + wv, tB = cb + 4 + wv;
            if (tA < ntiles) CMPS(k0, v0, tA, tA - cb);
            const int nA = cb + 8 + wv;
            if (nA < ntiles) LDK(k0, v0, nA);
            if (tB < ntiles) CMPS(k1, v1, tB, tB - cb);
            const int nB = cb + 12 + wv;
            if (nB < ntiles) LDK(k1, v1, nB);
            asm volatile("s_waitcnt lgkmcnt(0)" ::: "memory");
            __builtin_amdgcn_s_barrier();
            // flush 64 rows; each wave 16 rows, 1KB run per row
            const int rem = ntiles - cb;
            const int W = ((rem < CHUNK) ? rem : CHUNK) << 5;
            const size_t gb = (size_t)q0 * S_LEN + ((size_t)cb << 5);
            #pragma unroll
            for (int rr = 0; rr < 16; ++rr) {
                const int row = (rr << 2) + wv;                  // 0..63
                for (int c = lane << 2; c < W; c += 256)
                    nt_store4(outSb + gb + (size_t)row * S_LEN + c,
                              *(const f32x4*)&pstg[row * PSTR + c]);
            }
            asm volatile("s_waitcnt lgkmcnt(0)" ::: "memory");
            __builtin_amdgcn_s_barrier();
        }
    }

    // zero-fill masked region for all 64 rows (uniform kz)
    const int kz = ntiles << 5;
    {
        const int c0 = tid << 2;
        const f32x4 zz = {0.f,0.f,0.f,0.f};
        for (int r = 0; r < 64; ++r) {
            float* rowp = outSb + (size_t)(q0 + r) * S_LEN;
            for (int k = kz + c0; k < S_LEN; k += 1024)
                nt_store4(rowp + k, zz);
        }
    }

    // combine partial ctx across 4 waves (reuse pstg as [4][64][65])
    __syncthreads();
    {
        float* cb2 = pstg;
        const int base = wv * 4160;          // 64*65
        #pragma unroll
        for (int r = 0; r < 4; ++r) {
            cb2[base + (d0 + r) * 65 +  0 + l15] = cxa0[r];
            cb2[base + (d0 + r) * 65 + 16 + l15] = cxa1[r];
            cb2[base + (d0 + r) * 65 + 32 + l15] = cxa2[r];
            cb2[base + (d0 + r) * 65 + 48 + l15] = cxa3[r];
            cb2[base + (16 + d0 + r) * 65 +  0 + l15] = cxb0[r];
            cb2[base + (16 + d0 + r) * 65 + 16 + l15] = cxb1[r];
            cb2[base + (16 + d0 + r) * 65 + 32 + l15] = cxb2[r];
            cb2[base + (16 + d0 + r) * 65 + 48 + l15] = cxb3[r];
            cb2[base + (32 + d0 + r) * 65 +  0 + l15] = cxc0[r];
            cb2[base + (32 + d0 + r) * 65 + 16 + l15] = cxc1[r];
            cb2[base + (32 + d0 + r) * 65 + 32 + l15] = cxc2[r];
            cb2[base + (32 + d0 + r) * 65 + 48 + l15] = cxc3[r];
            cb2[base + (48 + d0 + r) * 65 +  0 + l15] = cxd0[r];
            cb2[base + (48 + d0 + r) * 65 + 16 + l15] = cxd1[r];
            cb2[base + (48 + d0 + r) * 65 + 32 + l15] = cxd2[r];
            cb2[base + (48 + d0 + r) * 65 + 48 + l15] = cxd3[r];
        }
        __syncthreads();
        const int dbase = (tid & 15) << 2;
        for (int rr = tid >> 4; rr < 64; rr += 16) {
            f32x4 acc = *(const f32x4*)&cb2[0 * 4160 + rr * 65 + dbase];
            #pragma unroll
            for (int w = 1; w < 4; ++w) {
                f32x4 p = *(const f32x4*)&cb2[w * 4160 + rr * 65 + dbase];
                acc[0] += p[0]; acc[1] += p[1]; acc[2] += p[2]; acc[3] += p[3];
            }
            *(f32x4*)(outCb + (size_t)(q0 + rr) * D_K + dbase) = acc;
        }
    }
}

// ---------------- fallback (R0 kernel, proven) if ws too small ----------------
#define KSTRIDE 68
#define VSTRIDE 36
__global__ __launch_bounds__(256) void attn_causal_fb(
    const float* __restrict__ Q, const float* __restrict__ K,
    const float* __restrict__ V, float* __restrict__ outC,
    float* __restrict__ outS)
{
    __shared__ short Klds[32 * KSTRIDE];
    __shared__ short Vlds[64 * VSTRIDE];
    const int bh = blockIdx.x >> 5, q0 = (blockIdx.x & 31) << 6;
    const int tid = threadIdx.x, lane = tid & 63, wv = tid >> 6;
    const int q0w = q0 + (wv << 4), l15 = lane & 15, d0 = (lane >> 4) << 2;
    const int qg = q0w + l15, qhi = q0w + 15;
    const float* Kb = K + (size_t)bh * S_LEN * D_K;
    const float* Vb = V + (size_t)bh * S_LEN * D_K;
    float* outSb = outS + (size_t)bh * S_LEN * S_LEN;
    float* outCb = outC + (size_t)bh * S_LEN * D_K;
    s16x8 qf0, qf1;
    {
        const float4* qp = (const float4*)(Q + ((size_t)bh * S_LEN + qg) * D_K);
        qf0 = cat(cvt4(qp[d0 >> 2]), cvt4(qp[(d0 + 16) >> 2]));
        qf1 = cat(cvt4(qp[(d0 + 32) >> 2]), cvt4(qp[(d0 + 48) >> 2]));
    }
    const int npairs = (q0 >> 5) + 2;
    const float scale = 0.125f;
    float lsum = 0.f;
    for (int p = 0; p < npairs; ++p) {
        const int k0 = p << 5;
        for (int i = tid; i < 512; i += 256) {
            const int r = i >> 4, c = (i & 15) << 2;
            float4 f = *(const float4*)(Kb + (size_t)(k0 + r) * D_K + c);
            *(s16x4*)&Klds[r * KSTRIDE + c] = cvt4(f);
        }
        __syncthreads();
        if (k0 <= qhi) {
            #pragma unroll
            for (int s = 0; s < 2; ++s) {
                const short* kp = &Klds[(16 * s + l15) * KSTRIDE + d0];
                s16x8 a0 = cat(*(const s16x4*)kp, *(const s16x4*)(kp + 16));
                s16x8 a1 = cat(*(const s16x4*)(kp + 32), *(const s16x4*)(kp + 48));
                f32x4 c1 = {0.f,0.f,0.f,0.f};
                c1 = MFMA(a0, qf0, c1, 0,0,0);
                c1 = MFMA(a1, qf1, c1, 0,0,0);
                const int kbase = k0 + 16 * s + d0;
                #pragma unroll
                for (int r = 0; r < 4; ++r)
                    if (kbase + r <= qg) lsum += __expf(c1[r] * scale);
            }
        }
        __syncthreads();
    }
    lsum += __shfl_xor(lsum, 16);
    lsum += __shfl_xor(lsum, 32);
    const float rinv = 1.f / lsum;
    f32x4 ctx[4] = {{0,0,0,0},{0,0,0,0},{0,0,0,0},{0,0,0,0}};
    for (int p = 0; p < npairs; ++p) {
        const int k0 = p << 5;
        for (int i = tid; i < 512; i += 256) {
            const int r = i >> 4, c = (i & 15) << 2;
            float4 f = *(const float4*)(Kb + (size_t)(k0 + r) * D_K + c);
            *(s16x4*)&Klds[r * KSTRIDE + c] = cvt4(f);
            float4 gg = *(const float4*)(Vb + (size_t)(k0 + r) * D_K + c);
            Vlds[(c + 0) * VSTRIDE + r] = f2bf(gg.x);
            Vlds[(c + 1) * VSTRIDE + r] = f2bf(gg.y);
            Vlds[(c + 2) * VSTRIDE + r] = f2bf(gg.z);
            Vlds[(c + 3) * VSTRIDE + r] = f2bf(gg.w);
        }
        __syncthreads();
        if (k0 <= qhi) {
            s16x8 pf;
            #pragma unroll
            for (int s = 0; s < 2; ++s) {
                const short* kp = &Klds[(16 * s + l15) * KSTRIDE + d0];
                s16x8 a0 = cat(*(const s16x4*)kp, *(const s16x4*)(kp + 16));
                s16x8 a1 = cat(*(const s16x4*)(kp + 32), *(const s16x4*)(kp + 48));
                f32x4 c1 = {0.f,0.f,0.f,0.f};
                c1 = MFMA(a0, qf0, c1, 0,0,0);
                c1 = MFMA(a1, qf1, c1, 0,0,0);
                const int kbase = k0 + 16 * s + d0;
                f32x4 pw;
                #pragma unroll
                for (int r = 0; r < 4; ++r) {
                    float pe = (kbase + r <= qg) ? __expf(c1[r] * scale) * rinv : 0.f;
                    pw[r] = pe;
                    pf[4 * s + r] = f2bf(pe);
                }
                *(f32x4*)(outSb + (size_t)qg * S_LEN + kbase) = pw;
            }
            #pragma unroll
            for (int db = 0; db < 4; ++db) {
                const short* vp = &Vlds[(db * 16 + l15) * VSTRIDE + d0];
                s16x8 b = cat(*(const s16x4*)vp, *(const s16x4*)(vp + 16));
                ctx[db] = MFMA(pf, b, ctx[db], 0,0,0);
            }
        }
        __syncthreads();
    }
    #pragma unroll
    for (int db = 0; db < 4; ++db)
        #pragma unroll
        for (int r = 0; r < 4; ++r)
            outCb[(size_t)(q0w + d0 + r) * D_K + db * 16 + l15] = ctx[db][r];
    const int kz = ((qhi >> 5) + 1) << 5;
    const f32x4 z = {0.f,0.f,0.f,0.f};
    for (int r = 0; r < 16; ++r) {
        float* rowp = outSb + (size_t)(q0w + r) * S_LEN;
        for (int k = kz + (lane << 2); k < S_LEN; k += 256)
            *(f32x4*)(rowp + k) = z;
    }
}

extern "C" void kernel_launch(void* const* d_in, const int* in_sizes, int n_in,
                              void* d_out, int out_size, void* d_ws, size_t ws_size,
                              hipStream_t stream) {
    const float* Q = (const float*)d_in[0];
    const float* K = (const float*)d_in[1];
    const float* V = (const float*)d_in[2];
    float* outC = (float*)d_out;
    float* outS = (float*)d_out + (size_t)NBH * S_LEN * D_K;

    const size_t kb_elems = (size_t)NBH * S_LEN * D_K;
    const size_t vt_elems = (size_t)NBH * D_K * VT_STRIDE;
    const size_t need = (kb_elems + vt_elems) * sizeof(short);

    if (ws_size >= need) {
        short* Kb = (short*)d_ws;
        short* VT = Kb + kb_elems;
        preconv<<<dim3(NBH * 64), dim3(256), 0, stream>>>(K, V, Kb, VT);
        attn_quad<<<dim3(1024), dim3(256), 0, stream>>>(Q, Kb, VT, outC, outS);
    } else {
        attn_causal_fb<<<dim3(1024), dim3(256), 0, stream>>>(Q, K, V, outC, outS);
    }
}

// Round 24
// 147.077 us; speedup vs baseline: 1.2861x; 1.1091x over previous
//
#include <hip/hip_runtime.h>
#include <stdint.h>

typedef float  f32x4  __attribute__((ext_vector_type(4)));
typedef short  s16x4  __attribute__((ext_vector_type(4)));
typedef short  s16x8  __attribute__((ext_vector_type(8)));

#define S_LEN 2048
#define D_K   64
#define NBH   32
#define VT_STRIDE (S_LEN + 32)
#define MFMA  __builtin_amdgcn_mfma_f32_16x16x32_bf16

__device__ __forceinline__ short f2bf(float f) {
    uint32_t u = __builtin_bit_cast(uint32_t, f);
    u += 0x7fffu + ((u >> 16) & 1u);           // RNE
    return (short)(u >> 16);
}
__device__ __forceinline__ float bf2f(short s) {
    uint32_t u = ((uint32_t)(uint16_t)s) << 16;
    return __builtin_bit_cast(float, u);
}
__device__ __forceinline__ s16x4 cvt4(float4 f) {
    s16x4 r; r[0] = f2bf(f.x); r[1] = f2bf(f.y); r[2] = f2bf(f.z); r[3] = f2bf(f.w);
    return r;
}
__device__ __forceinline__ s16x8 cat(s16x4 a, s16x4 b) {
    return __builtin_shufflevector(a, b, 0, 1, 2, 3, 4, 5, 6, 7);
}
__device__ __forceinline__ void nt_store4(float* p, f32x4 v) {
    __builtin_nontemporal_store(v, (f32x4*)p);
}

// ---- pre-pass: K -> bf16 FRAG-PERMUTED rows, V -> bf16 transposed, k-permuted ----
__global__ __launch_bounds__(256) void preconv(
    const float* __restrict__ K, const float* __restrict__ V,
    short* __restrict__ Kb, short* __restrict__ VT)
{
    const int bh  = blockIdx.x >> 6;
    const int seg = blockIdx.x & 63;
    const int tid = threadIdx.x;
    const float* Ks = K + ((size_t)bh * S_LEN + seg * 32) * D_K;
    const float* Vs = V + ((size_t)bh * S_LEN + seg * 32) * D_K;
    short* Kd  = Kb + ((size_t)bh * S_LEN + seg * 32) * D_K;
    short* VTd = VT + (size_t)bh * D_K * VT_STRIDE + seg * 32;

    for (int i = tid; i < 512; i += 256) {
        const int r = i >> 4, ci = i & 15;
        float4 f = *(const float4*)(Ks + r * D_K + (ci << 2));
        const int jj = ((ci & 3) << 1) + ((ci >> 2) & 1) + ((ci >> 3) << 3);
        *(s16x4*)(Kd + r * D_K + (jj << 2)) = cvt4(f);
    }
    for (int i = tid; i < 512; i += 256) {
        const int r = i & 31, c = (i >> 5) << 2;
        float4 f = *(const float4*)(Vs + r * D_K + c);
        const int rp = (((r & 15) >> 2) << 3) + (((r >> 4) & 1) << 2) + (r & 3);
        VTd[(size_t)(c + 0) * VT_STRIDE + rp] = f2bf(f.x);
        VTd[(size_t)(c + 1) * VT_STRIDE + rp] = f2bf(f.y);
        VTd[(size_t)(c + 2) * VT_STRIDE + rp] = f2bf(f.z);
        VTd[(size_t)(c + 3) * VT_STRIDE + rp] = f2bf(f.w);
    }
}

// ---- single-pass pair kernel: ONE QK^T pass; bf16 exp stash in 128KB LDS;
// ---- unnormalized PV (scaled at end, PER OUTPUT ROW d0+r); 8KB/row mega-flush ----
#define SSTR 2056    // shorts per stash row (2048 + 8 pad)
__global__ __launch_bounds__(256) void attn_sp(
    const float* __restrict__ Q, const short* __restrict__ Kb,
    const short* __restrict__ VT, float* __restrict__ outC,
    float* __restrict__ outS)
{
    __shared__ __align__(16) char smem[32 * SSTR * 2];   // 131.6 KB stash / combine
    __shared__ float lbuf[4][32];

    const int tid = threadIdx.x, lane = tid & 63, wv = tid >> 6;
    const int xcd = blockIdx.x & 7;
    const int idx = blockIdx.x >> 3;             // 0..255
    const int bh  = (xcd << 2) + (idx >> 6);     // 0..31
    const int j   = 63 - (idx & 63);             // heavy pairs first
    const int q0  = j << 5;                      // strip a rows q0..+15, b rows +16..+31
    const int l15 = lane & 15;
    const int g   = lane >> 4;
    const int d0  = g << 2;
    const int qa  = q0 + l15;

    const short* Kbh = Kb + (size_t)bh * S_LEN * D_K;
    const short* VTh = VT + (size_t)bh * D_K * VT_STRIDE;
    float* outSb = outS + (size_t)bh * S_LEN * S_LEN;
    float* outCb = outC + (size_t)bh * S_LEN * D_K;
    short* sstash = (short*)smem;

    s16x8 qf0a, qf1a, qf0b, qf1b;
    {
        const float4* qp = (const float4*)(Q + ((size_t)bh * S_LEN + qa) * D_K);
        qf0a = cat(cvt4(qp[g]),     cvt4(qp[g + 4]));
        qf1a = cat(cvt4(qp[g + 8]), cvt4(qp[g + 12]));
        const float4* qp2 = (const float4*)(Q + ((size_t)bh * S_LEN + qa + 16) * D_K);
        qf0b = cat(cvt4(qp2[g]),     cvt4(qp2[g + 4]));
        qf1b = cat(cvt4(qp2[g + 8]), cvt4(qp2[g + 12]));
    }

    const int ntiles = j + 1;
    const float scale = 0.125f;

    // ============ single pass: QK^T -> exp (unnorm) -> stash + sums + PV ============
    float la = 0.f, lb = 0.f;
    f32x4 z4 = {0.f,0.f,0.f,0.f};
    f32x4 cxa0 = z4, cxa1 = z4, cxa2 = z4, cxa3 = z4;
    f32x4 cxb0 = z4, cxb1 = z4, cxb2 = z4, cxb3 = z4;
    {
        s16x8 k0[4], v0[4], k1[4], v1[4];

        auto LDK = [&](s16x8* kk, s16x8* vv, int t) {
            const short* kp = Kbh + (((size_t)t << 5) + l15) * D_K + (g << 3);
            kk[0] = *(const s16x8*)(kp);
            kk[1] = *(const s16x8*)(kp + 32);
            kk[2] = *(const s16x8*)(kp + 16 * D_K);
            kk[3] = *(const s16x8*)(kp + 16 * D_K + 32);
            const short* vp = VTh + (size_t)l15 * VT_STRIDE + (t << 5) + (g << 3);
            vv[0] = *(const s16x8*)(vp);
            vv[1] = *(const s16x8*)(vp + 16 * VT_STRIDE);
            vv[2] = *(const s16x8*)(vp + 32 * VT_STRIDE);
            vv[3] = *(const s16x8*)(vp + 48 * VT_STRIDE);
        };
        auto CMPS = [&](const s16x8* kk, const s16x8* vv, int T) {
            f32x4 sa0 = z4, sa1 = z4, sb0 = z4, sb1 = z4;
            sa0 = MFMA(kk[0], qf0a, sa0, 0,0,0);
            sa0 = MFMA(kk[1], qf1a, sa0, 0,0,0);
            sa1 = MFMA(kk[2], qf0a, sa1, 0,0,0);
            sa1 = MFMA(kk[3], qf1a, sa1, 0,0,0);
            sb0 = MFMA(kk[0], qf0b, sb0, 0,0,0);
            sb0 = MFMA(kk[1], qf1b, sb0, 0,0,0);
            sb1 = MFMA(kk[2], qf0b, sb1, 0,0,0);
            sb1 = MFMA(kk[3], qf1b, sb1, 0,0,0);
            s16x8 pfa, pfb;
            if (T < j) {
                #pragma unroll
                for (int r = 0; r < 4; ++r) {
                    float e;
                    e = __expf(sa0[r] * scale); la += e; pfa[r]   = f2bf(e);
                    e = __expf(sa1[r] * scale); la += e; pfa[4+r] = f2bf(e);
                    e = __expf(sb0[r] * scale); lb += e; pfb[r]   = f2bf(e);
                    e = __expf(sb1[r] * scale); lb += e; pfb[4+r] = f2bf(e);
                }
            } else {      // diagonal tile: a1 fully masked; shared lane condition
                #pragma unroll
                for (int r = 0; r < 4; ++r) {
                    const bool c = (d0 + r) <= l15;
                    float e;
                    e = c ? __expf(sa0[r] * scale) : 0.f; la += e; pfa[r] = f2bf(e);
                    pfa[4+r] = 0;
                    e = __expf(sb0[r] * scale);           lb += e; pfb[r] = f2bf(e);
                    e = c ? __expf(sb1[r] * scale) : 0.f; lb += e; pfb[4+r] = f2bf(e);
                }
            }
            // stash bf16 exp (unnormalized); wave-private tiles, no barrier needed
            const int cbase = (T << 5) + d0;
            short* sA = &sstash[l15 * SSTR + cbase];
            *(s16x4*)(sA)      = __builtin_shufflevector(pfa, pfa, 0, 1, 2, 3);
            *(s16x4*)(sA + 16) = __builtin_shufflevector(pfa, pfa, 4, 5, 6, 7);
            short* sB = &sstash[(16 + l15) * SSTR + cbase];
            *(s16x4*)(sB)      = __builtin_shufflevector(pfb, pfb, 0, 1, 2, 3);
            *(s16x4*)(sB + 16) = __builtin_shufflevector(pfb, pfb, 4, 5, 6, 7);
            cxa0 = MFMA(pfa, vv[0], cxa0, 0,0,0);
            cxa1 = MFMA(pfa, vv[1], cxa1, 0,0,0);
            cxa2 = MFMA(pfa, vv[2], cxa2, 0,0,0);
            cxa3 = MFMA(pfa, vv[3], cxa3, 0,0,0);
            cxb0 = MFMA(pfb, vv[0], cxb0, 0,0,0);
            cxb1 = MFMA(pfb, vv[1], cxb1, 0,0,0);
            cxb2 = MFMA(pfb, vv[2], cxb2, 0,0,0);
            cxb3 = MFMA(pfb, vv[3], cxb3, 0,0,0);
        };

        int t = wv;
        if (t < ntiles) {
            LDK(k0, v0, t);
            while (t + 4 < ntiles) {
                LDK(k1, v1, t + 4);
                CMPS(k0, v0, t);
                t += 4;
                if (t + 4 < ntiles) {
                    LDK(k0, v0, t + 4);
                    CMPS(k1, v1, t);
                    t += 4;
                } else {
                    CMPS(k1, v1, t);
                    t += 4;
                    break;
                }
            }
            if (t < ntiles) CMPS(k0, v0, t);
        }
    }
    la += __shfl_xor(la, 16); la += __shfl_xor(la, 32);
    lb += __shfl_xor(lb, 16); lb += __shfl_xor(lb, 32);
    if (lane < 16) { lbuf[wv][l15] = la; lbuf[wv][16 + l15] = lb; }
    __syncthreads();
    // ---- FIX: ctx accumulator row is d0+r (C/D layout), not l15 ----
    #pragma unroll
    for (int r = 0; r < 4; ++r) {
        const float ra = 1.f / (lbuf[0][d0 + r] + lbuf[1][d0 + r]
                              + lbuf[2][d0 + r] + lbuf[3][d0 + r]);
        const float rb = 1.f / (lbuf[0][16 + d0 + r] + lbuf[1][16 + d0 + r]
                              + lbuf[2][16 + d0 + r] + lbuf[3][16 + d0 + r]);
        cxa0[r] *= ra; cxa1[r] *= ra; cxa2[r] *= ra; cxa3[r] *= ra;
        cxb0[r] *= rb; cxb1[r] *= rb; cxb2[r] *= rb; cxb3[r] *= rb;
    }

    // ============ mega-flush: each row one 8KB sequential run (P + zeros) ============
    const int kz = ntiles << 5;
    {
        #pragma unroll
        for (int rr8 = 0; rr8 < 8; ++rr8) {
            const int row = (wv << 3) + rr8;     // 0..31
            const float rinv_r = 1.f /
                (lbuf[0][row] + lbuf[1][row] + lbuf[2][row] + lbuf[3][row]);
            float* rowp = outSb + (size_t)(q0 + row) * S_LEN;
            const short* srow = &sstash[row * SSTR];
            for (int c = lane << 2; c < S_LEN; c += 256) {
                f32x4 v;
                if (c < kz) {
                    s16x4 sv = *(const s16x4*)(srow + c);
                    v[0] = bf2f(sv[0]) * rinv_r;
                    v[1] = bf2f(sv[1]) * rinv_r;
                    v[2] = bf2f(sv[2]) * rinv_r;
                    v[3] = bf2f(sv[3]) * rinv_r;
                } else {
                    v[0] = 0.f; v[1] = 0.f; v[2] = 0.f; v[3] = 0.f;
                }
                nt_store4(rowp + c, v);
            }
        }
    }

    // ============ ctx combine (reuse stash memory as [4][32][65] f32) ============
    __syncthreads();   // flush reads of stash complete
    {
        float* cb2 = (float*)smem;
        const int base = wv * 2080;              // 32*65
        #pragma unroll
        for (int r = 0; r < 4; ++r) {
            cb2[base + (d0 + r) * 65 +  0 + l15] = cxa0[r];
            cb2[base + (d0 + r) * 65 + 16 + l15] = cxa1[r];
            cb2[base + (d0 + r) * 65 + 32 + l15] = cxa2[r];
            cb2[base + (d0 + r) * 65 + 48 + l15] = cxa3[r];
            cb2[base + (16 + d0 + r) * 65 +  0 + l15] = cxb0[r];
            cb2[base + (16 + d0 + r) * 65 + 16 + l15] = cxb1[r];
            cb2[base + (16 + d0 + r) * 65 + 32 + l15] = cxb2[r];
            cb2[base + (16 + d0 + r) * 65 + 48 + l15] = cxb3[r];
        }
        __syncthreads();
        const int dbase = (tid & 15) << 2;
        for (int rr = tid >> 4; rr < 32; rr += 16) {
            f32x4 acc = *(const f32x4*)&cb2[0 * 2080 + rr * 65 + dbase];
            #pragma unroll
            for (int w = 1; w < 4; ++w) {
                f32x4 p = *(const f32x4*)&cb2[w * 2080 + rr * 65 + dbase];
                acc[0] += p[0]; acc[1] += p[1]; acc[2] += p[2]; acc[3] += p[3];
            }
            *(f32x4*)(outCb + (size_t)(q0 + rr) * D_K + dbase) = acc;
        }
    }
}

// ---------------- fallback (R0 kernel, proven) if ws too small ----------------
#define KSTRIDE 68
#define VSTRIDE 36
__global__ __launch_bounds__(256) void attn_causal_fb(
    const float* __restrict__ Q, const float* __restrict__ K,
    const float* __restrict__ V, float* __restrict__ outC,
    float* __restrict__ outS)
{
    __shared__ short Klds[32 * KSTRIDE];
    __shared__ short Vlds[64 * VSTRIDE];
    const int bh = blockIdx.x >> 5, q0 = (blockIdx.x & 31) << 6;
    const int tid = threadIdx.x, lane = tid & 63, wv = tid >> 6;
    const int q0w = q0 + (wv << 4), l15 = lane & 15, d0 = (lane >> 4) << 2;
    const int qg = q0w + l15, qhi = q0w + 15;
    const float* Kb = K + (size_t)bh * S_LEN * D_K;
    const float* Vb = V + (size_t)bh * S_LEN * D_K;
    float* outSb = outS + (size_t)bh * S_LEN * S_LEN;
    float* outCb = outC + (size_t)bh * S_LEN * D_K;
    s16x8 qf0, qf1;
    {
        const float4* qp = (const float4*)(Q + ((size_t)bh * S_LEN + qg) * D_K);
        qf0 = cat(cvt4(qp[d0 >> 2]), cvt4(qp[(d0 + 16) >> 2]));
        qf1 = cat(cvt4(qp[(d0 + 32) >> 2]), cvt4(qp[(d0 + 48) >> 2]));
    }
    const int npairs = (q0 >> 5) + 2;
    const float scale = 0.125f;
    float lsum = 0.f;
    for (int p = 0; p < npairs; ++p) {
        const int k0 = p << 5;
        for (int i = tid; i < 512; i += 256) {
            const int r = i >> 4, c = (i & 15) << 2;
            float4 f = *(const float4*)(Kb + (size_t)(k0 + r) * D_K + c);
            *(s16x4*)&Klds[r * KSTRIDE + c] = cvt4(f);
        }
        __syncthreads();
        if (k0 <= qhi) {
            #pragma unroll
            for (int s = 0; s < 2; ++s) {
                const short* kp = &Klds[(16 * s + l15) * KSTRIDE + d0];
                s16x8 a0 = cat(*(const s16x4*)kp, *(const s16x4*)(kp + 16));
                s16x8 a1 = cat(*(const s16x4*)(kp + 32), *(const s16x4*)(kp + 48));
                f32x4 c1 = {0.f,0.f,0.f,0.f};
                c1 = MFMA(a0, qf0, c1, 0,0,0);
                c1 = MFMA(a1, qf1, c1, 0,0,0);
                const int kbase = k0 + 16 * s + d0;
                #pragma unroll
                for (int r = 0; r < 4; ++r)
                    if (kbase + r <= qg) lsum += __expf(c1[r] * scale);
            }
        }
        __syncthreads();
    }
    lsum += __shfl_xor(lsum, 16);
    lsum += __shfl_xor(lsum, 32);
    const float rinv = 1.f / lsum;
    f32x4 ctx[4] = {{0,0,0,0},{0,0,0,0},{0,0,0,0},{0,0,0,0}};
    for (int p = 0; p < npairs; ++p) {
        const int k0 = p << 5;
        for (int i = tid; i < 512; i += 256) {
            const int r = i >> 4, c = (i & 15) << 2;
            float4 f = *(const float4*)(Kb + (size_t)(k0 + r) * D_K + c);
            *(s16x4*)&Klds[r * KSTRIDE + c] = cvt4(f);
            float4 gg = *(const float4*)(Vb + (size_t)(k0 + r) * D_K + c);
            Vlds[(c + 0) * VSTRIDE + r] = f2bf(gg.x);
            Vlds[(c + 1) * VSTRIDE + r] = f2bf(gg.y);
            Vlds[(c + 2) * VSTRIDE + r] = f2bf(gg.z);
            Vlds[(c + 3) * VSTRIDE + r] = f2bf(gg.w);
        }
        __syncthreads();
        if (k0 <= qhi) {
            s16x8 pf;
            #pragma unroll
            for (int s = 0; s < 2; ++s) {
                const short* kp = &Klds[(16 * s + l15) * KSTRIDE + d0];
                s16x8 a0 = cat(*(const s16x4*)kp, *(const s16x4*)(kp + 16));
                s16x8 a1 = cat(*(const s16x4*)(kp + 32), *(const s16x4*)(kp + 48));
                f32x4 c1 = {0.f,0.f,0.f,0.f};
                c1 = MFMA(a0, qf0, c1, 0,0,0);
                c1 = MFMA(a1, qf1, c1, 0,0,0);
                const int kbase = k0 + 16 * s + d0;
                f32x4 pw;
                #pragma unroll
                for (int r = 0; r < 4; ++r) {
                    float pe = (kbase + r <= qg) ? __expf(c1[r] * scale) * rinv : 0.f;
                    pw[r] = pe;
                    pf[4 * s + r] = f2bf(pe);
                }
                *(f32x4*)(outSb + (size_t)qg * S_LEN + kbase) = pw;
            }
            #pragma unroll
            for (int db = 0; db < 4; ++db) {
                const short* vp = &Vlds[(db * 16 + l15) * VSTRIDE + d0];
                s16x8 b = cat(*(const s16x4*)vp, *(const s16x4*)(vp + 16));
                ctx[db] = MFMA(pf, b, ctx[db], 0,0,0);
            }
        }
        __syncthreads();
    }
    #pragma unroll
    for (int db = 0; db < 4; ++db)
        #pragma unroll
        for (int r = 0; r < 4; ++r)
            outCb[(size_t)(q0w + d0 + r) * D_K + db * 16 + l15] = ctx[db][r];
    const int kz = ((qhi >> 5) + 1) << 5;
    const f32x4 z = {0.f,0.f,0.f,0.f};
    for (int r = 0; r < 16; ++r) {
        float* rowp = outSb + (size_t)(q0w + r) * S_LEN;
        for (int k = kz + (lane << 2); k < S_LEN; k += 256)
            *(f32x4*)(rowp + k) = z;
    }
}

extern "C" void kernel_launch(void* const* d_in, const int* in_sizes, int n_in,
                              void* d_out, int out_size, void* d_ws, size_t ws_size,
                              hipStream_t stream) {
    const float* Q = (const float*)d_in[0];
    const float* K = (const float*)d_in[1];
    const float* V = (const float*)d_in[2];
    float* outC = (float*)d_out;
    float* outS = (float*)d_out + (size_t)NBH * S_LEN * D_K;

    const size_t kb_elems = (size_t)NBH * S_LEN * D_K;
    const size_t vt_elems = (size_t)NBH * D_K * VT_STRIDE;
    const size_t need = (kb_elems + vt_elems) * sizeof(short);

    if (ws_size >= need) {
        short* Kb = (short*)d_ws;
        short* VT = Kb + kb_elems;
        preconv<<<dim3(NBH * 64), dim3(256), 0, stream>>>(K, V, Kb, VT);
        attn_sp<<<dim3(2048), dim3(256), 0, stream>>>(Q, Kb, VT, outC, outS);
    } else {
        attn_causal_fb<<<dim3(1024), dim3(256), 0, stream>>>(Q, K, V, outC, outS);
    }
}